// Round 6
// baseline (251.087 us; speedup 1.0000x reference)
//
#include <hip/hip_runtime.h>
#include <math.h>

#define TOK 4096
#define DM  512
#define HF  2048
#define NE  8

typedef __bf16 bf16x8 __attribute__((ext_vector_type(8)));
typedef float  floatx4 __attribute__((ext_vector_type(4)));

// float -> bf16 (round-to-nearest-even), raw ushort bits
__device__ __forceinline__ unsigned short f2b(float f) {
    union { float f; unsigned u; } v; v.f = f;
    return (unsigned short)((v.u + 0x7fffu + ((v.u >> 16) & 1u)) >> 16);
}

// async global->LDS, 16 bytes per lane (dest = wave-uniform base + lane*16)
__device__ __forceinline__ void load_lds16(const void* g, void* l) {
    __builtin_amdgcn_global_load_lds(
        (__attribute__((address_space(1))) unsigned int*)g,
        (__attribute__((address_space(3))) unsigned int*)l, 16, 0, 0);
}

// one wave per token: logits = x[t] @ Wr + br ; routes[t] = argmax.
// NO atomics (round-3 lesson: 4096 device atomics on one cache line = 54 us).
__global__ __launch_bounds__(256)
void k_router(const float* __restrict__ x, const float* __restrict__ Wr,
              const float* __restrict__ br, int* __restrict__ routes) {
    int t = blockIdx.x * 4 + (threadIdx.x >> 6);
    int lane = threadIdx.x & 63;
    float acc[NE];
#pragma unroll
    for (int e = 0; e < NE; e++) acc[e] = 0.f;
    const float* xr = x + (size_t)t * DM;
#pragma unroll
    for (int d0 = 0; d0 < DM; d0 += 64) {
        float xv = xr[d0 + lane];
        const float* w = Wr + (size_t)(d0 + lane) * NE;
#pragma unroll
        for (int e = 0; e < NE; e++) acc[e] += xv * w[e];
    }
#pragma unroll
    for (int off = 32; off > 0; off >>= 1) {
#pragma unroll
        for (int e = 0; e < NE; e++) acc[e] += __shfl_down(acc[e], off, 64);
    }
    if (lane == 0) {
        int best = 0; float bv = acc[0] + br[0];
#pragma unroll
        for (int e = 1; e < NE; e++) {
            float v = acc[e] + br[e];
            if (v > bv) { bv = v; best = e; }   // strict > == first-max (jnp.argmax)
        }
        routes[t] = best;
    }
}

// Single block: histogram + prefix + perm placement, all contention in LDS.
__global__ __launch_bounds__(1024)
void k_organize(const int* __restrict__ routes, int* __restrict__ offsets,
                int* __restrict__ perm) {
    __shared__ int cnt[NE], cur[NE], off[NE + 1];
    int tid = threadIdx.x;
    if (tid < NE) { cnt[tid] = 0; cur[tid] = 0; }
    __syncthreads();
    int t0 = tid * 4;
    int4 r = *(const int4*)&routes[t0];
    atomicAdd(&cnt[r.x], 1); atomicAdd(&cnt[r.y], 1);
    atomicAdd(&cnt[r.z], 1); atomicAdd(&cnt[r.w], 1);
    __syncthreads();
    if (tid == 0) {
        int s = 0;
#pragma unroll
        for (int e = 0; e < NE; e++) { off[e] = s; s += cnt[e]; }
        off[NE] = s;
    }
    __syncthreads();
    int p;
    p = atomicAdd(&cur[r.x], 1); perm[off[r.x] + p] = t0;
    p = atomicAdd(&cur[r.y], 1); perm[off[r.y] + p] = t0 + 1;
    p = atomicAdd(&cur[r.z], 1); perm[off[r.z] + p] = t0 + 2;
    p = atomicAdd(&cur[r.w], 1); perm[off[r.w] + p] = t0 + 3;
    if (tid < NE + 1) offsets[tid] = off[tid];
}

// gather x rows into expert-grouped bf16 matrix xg[g][d]; 4 rows per block
__global__ __launch_bounds__(256)
void k_gather(const float* __restrict__ x, const int* __restrict__ perm,
              unsigned short* __restrict__ xg) {
    int g = blockIdx.x * 4 + (threadIdx.x >> 6);
    int lane = threadIdx.x & 63;
    int t = perm[g];
    const float4* src = (const float4*)(x + (size_t)t * DM);
    unsigned short* dst = xg + (size_t)g * DM;
#pragma unroll
    for (int i = 0; i < 2; i++) {
        int idx = lane + i * 64;
        float4 v = src[idx];
        ushort4 o; o.x = f2b(v.x); o.y = f2b(v.y); o.z = f2b(v.z); o.w = f2b(v.w);
        *(ushort4*)(dst + idx * 4) = o;
    }
}

// Both weight transposes in ONE dispatch. blockIdx.x < 256: W1 tile; else W2.
// [E][K][N] fp32 -> [E][N][K] bf16, 64x64 tiles.
__global__ __launch_bounds__(256)
void k_transpose(const float* __restrict__ W1, unsigned short* __restrict__ W1t,
                 const float* __restrict__ W2, unsigned short* __restrict__ W2t) {
    int e = blockIdx.z;
    int bt = blockIdx.x;
    const float* src; unsigned short* dst; int K, N, n0, k0;
    if (bt < 256) {            // W1: K=DM(512)=8 k-tiles, N=HF(2048)=32 n-tiles
        K = DM; N = HF;
        n0 = (bt & 31) * 64; k0 = (bt >> 5) * 64;
        src = W1 + (size_t)e * K * N; dst = W1t + (size_t)e * N * K;
    } else {                   // W2: K=HF(2048)=32 k-tiles, N=DM(512)=8 n-tiles
        bt -= 256; K = HF; N = DM;
        n0 = (bt & 7) * 64; k0 = (bt >> 3) * 64;
        src = W2 + (size_t)e * K * N; dst = W2t + (size_t)e * N * K;
    }
    __shared__ unsigned short tile[64][68];
    int tid = threadIdx.x;
    int tr = tid >> 4;   // 0..15
    int tc = tid & 15;   // 0..15
#pragma unroll
    for (int rr = 0; rr < 4; rr++) {
        int r = tr * 4 + rr;
        const float4 v = *(const float4*)(src + (size_t)(k0 + r) * N + n0 + tc * 4);
        tile[r][tc * 4 + 0] = f2b(v.x);
        tile[r][tc * 4 + 1] = f2b(v.y);
        tile[r][tc * 4 + 2] = f2b(v.z);
        tile[r][tc * 4 + 3] = f2b(v.w);
    }
    __syncthreads();
#pragma unroll
    for (int rr = 0; rr < 4; rr++) {
        int nrow = tr * 4 + rr;
        ushort4 o;
        o.x = tile[tc * 4 + 0][nrow];
        o.y = tile[tc * 4 + 1][nrow];
        o.z = tile[tc * 4 + 2][nrow];
        o.w = tile[tc * 4 + 3][nrow];
        *(ushort4*)(dst + (size_t)(n0 + nrow) * K + k0 + tc * 4) = o;
    }
}

// Grouped GEMM, SINGLE-WAVE blocks (round-6 redesign): C[64,64] per block.
// One wave owns the whole 64x64 tile with 4x4 16x16x32 fragments -> m97's
// 2:1 MFMA:ds_read ratio. No inter-wave barrier coupling: __syncthreads in a
// 1-wave workgroup is just this wave's own vmcnt drain (exactly the dbuf wait).
// 16 KB LDS/block -> 10 independent block-pipelines per CU.
// XOR bank swizzle: LDS slot (row, s) holds global k-chunk s ^ ((row>>1)&3).
// Applied on the GLOBAL side of global_load_lds (LDS dest must stay
// lane-linear); makes ds_read_b128 fragment reads hit all 8 bank-quads
// per 8-lane group (was ~8-way conflicted: 2.68M conflict cycles in r5).
// FC1: epilogue = GELU(acc + b1) -> hg (bf16).
// FC2: epilogue = acc + b2 -> out[perm[row]] (fp32), no split-K, no pbuf.
template <int KD, int ND, bool FC1>
__global__ __launch_bounds__(64, 3)
void k_gemm(const unsigned short* __restrict__ A,
            const unsigned short* __restrict__ Bt,
            const float* __restrict__ bias,
            unsigned short* __restrict__ hg,
            float* __restrict__ out,
            const int* __restrict__ offsets,
            const int* __restrict__ perm) {
    const int e = blockIdx.z;
    const int seg0 = offsets[e];
    const int cnt  = offsets[e + 1] - seg0;
    const int m0 = blockIdx.y * 64;
    if (m0 >= cnt) return;
    const int n0 = blockIdx.x * 64;

    __shared__ unsigned short As[2][64 * 32];
    __shared__ unsigned short Bs[2][64 * 32];

    const unsigned short* Aexp = A + (size_t)seg0 * KD;
    const unsigned short* Bexp = Bt + (size_t)e * ND * KD;

    const int lane = threadIdx.x;
    // staging: lane -> LDS (row = 16i + (lane>>2), chunk slot lane&3);
    // global source chunk = slot ^ ((row>>1)&3) = (lane&3) ^ ((lane>>3)&3)
    const int sr = lane >> 2;
    const int sc = ((lane & 3) ^ ((lane >> 3) & 3)) * 8;   // ushort offset
    // fragment read: row = (lane&15) + 16t; slot = (lane>>4) ^ ((row>>1)&3)
    const int fRow = lane & 15;
    const int fChunk = (((lane >> 4) ^ ((lane >> 1) & 3))) * 8;

    auto stage = [&](int k0, int buf) {
#pragma unroll
        for (int i = 0; i < 4; i++) {
            load_lds16(Aexp + (size_t)(m0 + i * 16 + sr) * KD + k0 + sc,
                       (char*)As[buf] + i * 1024 + lane * 16);
            load_lds16(Bexp + (size_t)(n0 + i * 16 + sr) * KD + k0 + sc,
                       (char*)Bs[buf] + i * 1024 + lane * 16);
        }
    };

    floatx4 acc[4][4];
#pragma unroll
    for (int i = 0; i < 4; i++)
#pragma unroll
        for (int j = 0; j < 4; j++)
#pragma unroll
            for (int r = 0; r < 4; r++) acc[i][j][r] = 0.f;

    stage(0, 0);
    int cur = 0;
    for (int k0 = 0; k0 < KD; k0 += 32) {
        __syncthreads();   // 1-wave: vmcnt drain of buf `cur` staging only
        if (k0 + 32 < KD) stage(k0 + 32, cur ^ 1);   // prefetch overlaps MFMA
        bf16x8 af[4], bfr[4];
#pragma unroll
        for (int t = 0; t < 4; t++)
            af[t]  = *(const bf16x8*)&As[cur][(fRow + t * 16) * 32 + fChunk];
#pragma unroll
        for (int t = 0; t < 4; t++)
            bfr[t] = *(const bf16x8*)&Bs[cur][(fRow + t * 16) * 32 + fChunk];
#pragma unroll
        for (int i = 0; i < 4; i++)
#pragma unroll
            for (int j = 0; j < 4; j++)
                acc[i][j] = __builtin_amdgcn_mfma_f32_16x16x32_bf16(af[i], bfr[j], acc[i][j], 0, 0, 0);
        cur ^= 1;
    }

    // epilogue: C/D layout col=lane&15, row=(lane>>4)*4+reg
    const int rq = (lane >> 4) * 4;
    const int cl = lane & 15;
#pragma unroll
    for (int j = 0; j < 4; j++) {
        int col = n0 + j * 16 + cl;
        float bv = bias[(size_t)e * ND + col];
#pragma unroll
        for (int i = 0; i < 4; i++) {
#pragma unroll
            for (int r = 0; r < 4; r++) {
                int grow = m0 + i * 16 + rq + r;
                if (grow < cnt) {
                    float v = acc[i][j][r] + bv;
                    if constexpr (FC1) {
                        v = 0.5f * v * (1.0f + erff(v * 0.70710678118654752f)); // exact GELU
                        hg[(size_t)(seg0 + grow) * ND + col] = f2b(v);
                    } else {
                        int tok = perm[seg0 + grow];
                        out[(size_t)tok * ND + col] = v;
                    }
                }
            }
        }
    }
}

extern "C" void kernel_launch(void* const* d_in, const int* in_sizes, int n_in,
                              void* d_out, int out_size, void* d_ws, size_t ws_size,
                              hipStream_t stream) {
    const float* x  = (const float*)d_in[0];
    const float* Wr = (const float*)d_in[1];
    const float* br = (const float*)d_in[2];
    const float* W1 = (const float*)d_in[3];
    const float* b1 = (const float*)d_in[4];
    const float* W2 = (const float*)d_in[5];
    const float* b2 = (const float*)d_in[6];
    float* out = (float*)d_out;

    char* ws = (char*)d_ws;
    int* routes  = (int*)ws;            // [4096]
    int* perm    = routes + TOK;        // [4096]
    int* offsets = perm + TOK;          // [9]
    unsigned short* xg  = (unsigned short*)(ws + 65536);     // [4096][512]  bf16  (4 MB)
    unsigned short* hg  = xg + (size_t)TOK * DM;             // [4096][2048] bf16  (16 MB)
    unsigned short* W1t = hg + (size_t)TOK * HF;             // [E][H][D]    bf16  (16.8 MB)
    unsigned short* W2t = W1t + (size_t)NE * HF * DM;        // [E][D][H]    bf16  (16.8 MB)
    // fc1/fc2 A-tile overruns read past xg/hg ends into the next buffer
    // (valid memory, non-NaN bf16 bit patterns); rows >= cnt never stored.

    k_router<<<TOK / 4, 256, 0, stream>>>(x, Wr, br, routes);
    k_organize<<<1, 1024, 0, stream>>>(routes, offsets, perm);
    k_gather<<<TOK / 4, 256, 0, stream>>>(x, perm, xg);
    k_transpose<<<dim3(512, 1, NE), 256, 0, stream>>>(W1, W1t, W2, W2t);
    // fc1: 64x64 single-wave blocks -> ~2048 active, ~8-10 independent waves/CU.
    k_gemm<DM, HF, true ><<<dim3(HF / 64, TOK / 64, NE), 64, 0, stream>>>(
        xg, W1t, b1, hg, nullptr, offsets, nullptr);
    // fc2: 64x64 single-wave, full K=2048, direct bias+scatter epilogue.
    k_gemm<HF, DM, false><<<dim3(DM / 64, TOK / 64, NE), 64, 0, stream>>>(
        hg, W2t, b2, nullptr, out, offsets, perm);
}

// Round 7
// 199.094 us; speedup vs baseline: 1.2612x; 1.2612x over previous
//
#include <hip/hip_runtime.h>
#include <math.h>

#define TOK 4096
#define DM  512
#define HF  2048
#define NE  8

typedef __bf16 bf16x8 __attribute__((ext_vector_type(8)));
typedef float  floatx16 __attribute__((ext_vector_type(16)));

// float -> bf16 (round-to-nearest-even), raw ushort bits
__device__ __forceinline__ unsigned short f2b(float f) {
    union { float f; unsigned u; } v; v.f = f;
    return (unsigned short)((v.u + 0x7fffu + ((v.u >> 16) & 1u)) >> 16);
}

// async global->LDS, 16 bytes per lane (dest = wave-uniform base + lane*16)
__device__ __forceinline__ void load_lds16(const void* g, void* l) {
    __builtin_amdgcn_global_load_lds(
        (__attribute__((address_space(1))) unsigned int*)g,
        (__attribute__((address_space(3))) unsigned int*)l, 16, 0, 0);
}

// one wave per token: logits = x[t] @ Wr + br ; routes[t] = argmax. NO atomics.
__global__ __launch_bounds__(256)
void k_router(const float* __restrict__ x, const float* __restrict__ Wr,
              const float* __restrict__ br, int* __restrict__ routes) {
    int t = blockIdx.x * 4 + (threadIdx.x >> 6);
    int lane = threadIdx.x & 63;
    float acc[NE];
#pragma unroll
    for (int e = 0; e < NE; e++) acc[e] = 0.f;
    const float* xr = x + (size_t)t * DM;
#pragma unroll
    for (int d0 = 0; d0 < DM; d0 += 64) {
        float xv = xr[d0 + lane];
        const float* w = Wr + (size_t)(d0 + lane) * NE;
#pragma unroll
        for (int e = 0; e < NE; e++) acc[e] += xv * w[e];
    }
#pragma unroll
    for (int off = 32; off > 0; off >>= 1) {
#pragma unroll
        for (int e = 0; e < NE; e++) acc[e] += __shfl_down(acc[e], off, 64);
    }
    if (lane == 0) {
        int best = 0; float bv = acc[0] + br[0];
#pragma unroll
        for (int e = 1; e < NE; e++) {
            float v = acc[e] + br[e];
            if (v > bv) { bv = v; best = e; }   // strict > == first-max (jnp.argmax)
        }
        routes[t] = best;
    }
}

// Single block: histogram + prefix + perm placement, all contention in LDS.
__global__ __launch_bounds__(1024)
void k_organize(const int* __restrict__ routes, int* __restrict__ offsets,
                int* __restrict__ perm) {
    __shared__ int cnt[NE], cur[NE], off[NE + 1];
    int tid = threadIdx.x;
    if (tid < NE) { cnt[tid] = 0; cur[tid] = 0; }
    __syncthreads();
    int t0 = tid * 4;
    int4 r = *(const int4*)&routes[t0];
    atomicAdd(&cnt[r.x], 1); atomicAdd(&cnt[r.y], 1);
    atomicAdd(&cnt[r.z], 1); atomicAdd(&cnt[r.w], 1);
    __syncthreads();
    if (tid == 0) {
        int s = 0;
#pragma unroll
        for (int e = 0; e < NE; e++) { off[e] = s; s += cnt[e]; }
        off[NE] = s;
    }
    __syncthreads();
    int p;
    p = atomicAdd(&cur[r.x], 1); perm[off[r.x] + p] = t0;
    p = atomicAdd(&cur[r.y], 1); perm[off[r.y] + p] = t0 + 1;
    p = atomicAdd(&cur[r.z], 1); perm[off[r.z] + p] = t0 + 2;
    p = atomicAdd(&cur[r.w], 1); perm[off[r.w] + p] = t0 + 3;
    if (tid < NE + 1) offsets[tid] = off[tid];
}

// gather x rows into expert-grouped bf16 matrix xg[g][d]; 4 rows per block
__global__ __launch_bounds__(256)
void k_gather(const float* __restrict__ x, const int* __restrict__ perm,
              unsigned short* __restrict__ xg) {
    int g = blockIdx.x * 4 + (threadIdx.x >> 6);
    int lane = threadIdx.x & 63;
    int t = perm[g];
    const float4* src = (const float4*)(x + (size_t)t * DM);
    unsigned short* dst = xg + (size_t)g * DM;
#pragma unroll
    for (int i = 0; i < 2; i++) {
        int idx = lane + i * 64;
        float4 v = src[idx];
        ushort4 o; o.x = f2b(v.x); o.y = f2b(v.y); o.z = f2b(v.z); o.w = f2b(v.w);
        *(ushort4*)(dst + idx * 4) = o;
    }
}

// Both weight transposes in ONE dispatch. blockIdx.x < 256: W1 tile; else W2.
// [E][K][N] fp32 -> [E][N][K] bf16, 64x64 tiles.
__global__ __launch_bounds__(256)
void k_transpose(const float* __restrict__ W1, unsigned short* __restrict__ W1t,
                 const float* __restrict__ W2, unsigned short* __restrict__ W2t) {
    int e = blockIdx.z;
    int bt = blockIdx.x;
    const float* src; unsigned short* dst; int K, N, n0, k0;
    if (bt < 256) {            // W1: K=DM(512)=8 k-tiles, N=HF(2048)=32 n-tiles
        K = DM; N = HF;
        n0 = (bt & 31) * 64; k0 = (bt >> 5) * 64;
        src = W1 + (size_t)e * K * N; dst = W1t + (size_t)e * N * K;
    } else {                   // W2: K=HF(2048)=32 k-tiles, N=DM(512)=8 n-tiles
        bt -= 256; K = HF; N = DM;
        n0 = (bt & 7) * 64; k0 = (bt >> 3) * 64;
        src = W2 + (size_t)e * K * N; dst = W2t + (size_t)e * N * K;
    }
    __shared__ unsigned short tile[64][68];
    int tid = threadIdx.x;
    int tr = tid >> 4;   // 0..15
    int tc = tid & 15;   // 0..15
#pragma unroll
    for (int rr = 0; rr < 4; rr++) {
        int r = tr * 4 + rr;
        const float4 v = *(const float4*)(src + (size_t)(k0 + r) * N + n0 + tc * 4);
        tile[r][tc * 4 + 0] = f2b(v.x);
        tile[r][tc * 4 + 1] = f2b(v.y);
        tile[r][tc * 4 + 2] = f2b(v.z);
        tile[r][tc * 4 + 3] = f2b(v.w);
    }
    __syncthreads();
#pragma unroll
    for (int rr = 0; rr < 4; rr++) {
        int nrow = tr * 4 + rr;
        ushort4 o;
        o.x = tile[tc * 4 + 0][nrow];
        o.y = tile[tc * 4 + 1][nrow];
        o.z = tile[tc * 4 + 2][nrow];
        o.w = tile[tc * 4 + 3][nrow];
        *(ushort4*)(dst + (size_t)(n0 + nrow) * K + k0 + tc * 4) = o;
    }
}

// Grouped GEMM (round-7): 128x128 block, 4 waves (2x2) of 64x64, BK=32,
// mfma_f32_32x32x16_bf16 (2x FLOP per LDS byte vs 16x16x32 — r5 showed the
// 4-wave loop is LDS-read-BW-bound), double-buffered LDS (r3), XOR bank
// swizzle on the global side of global_load_lds (r6: 0 conflicts).
// LDS slot (row, pc) holds k-chunk pc ^ ((row>>1)&3); 16B chunks.
// FC1 (KSPLIT=1): epilogue GELU(acc+b1) -> hg (bf16).
// FC2 (KSPLIT=4): K-slice partials -> pbuf[ks]; k_reduce sums + bias + scatter.
template <int KD, int ND, bool FC1, int KSPLIT>
__global__ __launch_bounds__(256)
void k_gemm(const unsigned short* __restrict__ A,
            const unsigned short* __restrict__ Bt,
            const float* __restrict__ bias,
            unsigned short* __restrict__ hg,
            float* __restrict__ pbuf,
            const int* __restrict__ offsets) {
    const int e  = blockIdx.z / KSPLIT;
    const int ks = blockIdx.z % KSPLIT;
    const int seg0 = offsets[e];
    const int cnt  = offsets[e + 1] - seg0;
    const int m0 = blockIdx.y * 128;
    if (m0 >= cnt) return;
    const int n0 = blockIdx.x * 128;

    __shared__ unsigned short As[2][128 * 32];
    __shared__ unsigned short Bs[2][128 * 32];

    const unsigned short* Aexp = A + (size_t)seg0 * KD;
    const unsigned short* Bexp = Bt + (size_t)e * ND * KD;

    const int tid  = threadIdx.x;
    const int lane = tid & 63;
    const int wave = tid >> 6;
    const int wm = (wave >> 1) * 64;   // wave M offset in block tile
    const int wn = (wave & 1) * 64;    // wave N offset

    // staging source swizzle: phys slot (row = fo>>6, pc = (fo>>4)&3)
    // holds global chunk c = pc ^ ((row>>1)&3)
    auto stage = [&](int k0, int buf) {
#pragma unroll
        for (int r = 0; r < 2; r++) {
            int fo  = tid * 16 + r * 4096;
            int row = fo >> 6;
            int c   = ((fo >> 4) & 3) ^ ((row >> 1) & 3);
            load_lds16(Aexp + (size_t)(m0 + row) * KD + k0 + c * 8, (char*)As[buf] + fo);
            load_lds16(Bexp + (size_t)(n0 + row) * KD + k0 + c * 8, (char*)Bs[buf] + fo);
        }
    };

    // fragment read addressing (32x32x16: m/n = lane&31, k = (lane>>5)*8 + j)
    const int fr = lane & 31;           // row within 32-row fragment group
    const int hi = lane >> 5;           // k-half selector
    const int q  = (lane >> 1) & 3;     // swizzle term ((row>>1)&3)
    // ushort offsets of the two k-steps' chunks, swizzled:
    const int sw[2] = { ((0 + hi) ^ q) * 8, ((2 + hi) ^ q) * 8 };
    const int aBase = (wm + fr) * 32;
    const int bBase = (wn + fr) * 32;

    floatx16 acc[2][2];
#pragma unroll
    for (int i = 0; i < 2; i++)
#pragma unroll
        for (int j = 0; j < 2; j++)
#pragma unroll
            for (int r = 0; r < 16; r++) acc[i][j][r] = 0.f;

    const int kBase = ks * (KD / KSPLIT);
    const int kEnd  = kBase + (KD / KSPLIT);
    stage(kBase, 0);
    int cur = 0;
    for (int k0 = kBase; k0 < kEnd; k0 += 32) {
        __syncthreads();   // buf `cur` staged; prior reads of cur^1 done
        if (k0 + 32 < kEnd) stage(k0 + 32, cur ^ 1);   // prefetch overlaps MFMA
#pragma unroll
        for (int kk = 0; kk < 2; kk++) {
            bf16x8 af[2], bf[2];
#pragma unroll
            for (int i = 0; i < 2; i++)
                af[i] = *(const bf16x8*)&As[cur][aBase + i * 1024 + sw[kk]];
#pragma unroll
            for (int j = 0; j < 2; j++)
                bf[j] = *(const bf16x8*)&Bs[cur][bBase + j * 1024 + sw[kk]];
#pragma unroll
            for (int i = 0; i < 2; i++)
#pragma unroll
                for (int j = 0; j < 2; j++)
                    acc[i][j] = __builtin_amdgcn_mfma_f32_32x32x16_bf16(af[i], bf[j], acc[i][j], 0, 0, 0);
        }
        cur ^= 1;
    }

    // epilogue: 32x32 C/D layout col=lane&31, row=(reg&3)+8*(reg>>2)+4*(lane>>5)
    const int rbase = 4 * hi;
#pragma unroll
    for (int i = 0; i < 2; i++) {
#pragma unroll
        for (int j = 0; j < 2; j++) {
            int col = n0 + wn + j * 32 + fr;
            float bv = FC1 ? bias[(size_t)e * ND + col] : 0.f;
#pragma unroll
            for (int r = 0; r < 16; r++) {
                int grow = m0 + wm + i * 32 + rbase + (r & 3) + 8 * (r >> 2);
                if (grow < cnt) {
                    float v = acc[i][j][r] + bv;
                    if constexpr (FC1) {
                        v = 0.5f * v * (1.0f + erff(v * 0.70710678118654752f)); // exact GELU
                        hg[(size_t)(seg0 + grow) * ND + col] = f2b(v);
                    } else {
                        pbuf[((size_t)ks * TOK + seg0 + grow) * ND + col] = v;
                    }
                }
            }
        }
    }
}

// out[perm[g]][:] = sum_ks pbuf[ks][g][:] + b2[e(g)][:]
__global__ __launch_bounds__(128)
void k_reduce(const float* __restrict__ pbuf, const int* __restrict__ perm,
              const int* __restrict__ offsets, const float* __restrict__ b2,
              float* __restrict__ out) {
    int g = blockIdx.x;
    int tok = perm[g];
    int e = 0;
#pragma unroll
    for (int i = 1; i < NE; i++) e += (g >= offsets[i]);
    int c = threadIdx.x * 4;
    float4 o = *(const float4*)&b2[(size_t)e * DM + c];
#pragma unroll
    for (int ks = 0; ks < 4; ks++) {
        float4 a = *(const float4*)&pbuf[((size_t)ks * TOK + g) * DM + c];
        o.x += a.x; o.y += a.y; o.z += a.z; o.w += a.w;
    }
    *(float4*)&out[(size_t)tok * DM + c] = o;
}

extern "C" void kernel_launch(void* const* d_in, const int* in_sizes, int n_in,
                              void* d_out, int out_size, void* d_ws, size_t ws_size,
                              hipStream_t stream) {
    const float* x  = (const float*)d_in[0];
    const float* Wr = (const float*)d_in[1];
    const float* br = (const float*)d_in[2];
    const float* W1 = (const float*)d_in[3];
    const float* b1 = (const float*)d_in[4];
    const float* W2 = (const float*)d_in[5];
    const float* b2 = (const float*)d_in[6];
    float* out = (float*)d_out;

    char* ws = (char*)d_ws;
    int* routes  = (int*)ws;            // [4096]
    int* perm    = routes + TOK;        // [4096]
    int* offsets = perm + TOK;          // [9]
    unsigned short* xg  = (unsigned short*)(ws + 65536);     // [4096][512]  bf16  (4 MB)
    unsigned short* hg  = xg + (size_t)TOK * DM;             // [4096][2048] bf16  (16 MB)
    unsigned short* W1t = hg + (size_t)TOK * HF;             // [E][H][D]    bf16  (16.8 MB)
    unsigned short* W2t = W1t + (size_t)NE * HF * DM;        // [E][D][H]    bf16  (16.8 MB)
    float* pbuf = (float*)(W2t + (size_t)NE * DM * HF);      // [4][4096][512] fp32 (32 MB)
    // GEMM A-tile overruns past xg/hg ends land in the next buffer (valid
    // memory, non-NaN bf16 bit patterns); rows >= cnt never stored.

    k_router<<<TOK / 4, 256, 0, stream>>>(x, Wr, br, routes);
    k_organize<<<1, 1024, 0, stream>>>(routes, offsets, perm);
    k_gather<<<TOK / 4, 256, 0, stream>>>(x, perm, xg);
    k_transpose<<<dim3(512, 1, NE), 256, 0, stream>>>(W1, W1t, W2, W2t);
    // fc1: 128x128 blocks -> ~512 active (2/CU, 8 waves/CU), 16 K-iters.
    k_gemm<DM, HF, true, 1><<<dim3(HF / 128, TOK / 128, NE), 256, 0, stream>>>(
        xg, W1t, b1, hg, nullptr, offsets);
    // fc2: split-K=4 -> ~512 active blocks, 16 K-iters each; no atomics.
    k_gemm<HF, DM, false, 4><<<dim3(DM / 128, TOK / 128, NE * 4), 256, 0, stream>>>(
        hg, W2t, nullptr, nullptr, pbuf, offsets);
    k_reduce<<<TOK, 128, 0, stream>>>(pbuf, perm, offsets, b2, out);
}